// Round 4
// baseline (49.722 us; speedup 1.0000x reference)
//
#include <hip/hip_runtime.h>
#include <math.h>

#define BATCH 4096
#define NPTS 1000
#define WAVE_F 288   // floats of LDS per wave region

// Within-wave LDS producer->consumer fence: LDS ops are memory ops, so the
// memory clobber orders them; sched_barrier stops scheduler migration.
#define WSYNC() do { asm volatile("s_waitcnt lgkmcnt(0)" ::: "memory"); \
                     __builtin_amdgcn_sched_barrier(0); } while (0)

__global__ __launch_bounds__(256) void net2_wave(
    const float* __restrict__ x,   // (B,8)
    const float* __restrict__ P,   // (B,6,2,1)
    const float* __restrict__ W1,  // (128,8)
    const float* __restrict__ b1,  // (128)
    const float* __restrict__ W2,  // (128,128)
    const float* __restrict__ b2,  // (128)
    const float* __restrict__ W3,  // (5,128)
    const float* __restrict__ b3,  // (5)
    float* __restrict__ out_integ, // (B)
    float* __restrict__ out_knots) // (B,12)
{
    __shared__ float lds[4 * WAVE_F];
    const int tid  = threadIdx.x;
    const int wv   = tid >> 6;
    const int lane = tid & 63;
    const int b    = blockIdx.x * 4 + wv;

    float* L    = &lds[wv * WAVE_F];
    float* Lh1  = L;          // 128 floats
    float* Lkt  = L + 128;    // 16 (12 used + pad)
    float* LA   = L + 144;    // 80  (8 rows x 10: cols 0..7 = A, 8/9 = rhs x/y)
    float* LQ   = L + 224;    // 14  (7 x 2)
    float* LR   = L + 240;    // 12  (6 x 2)
    float* Lrcp = L + 256;    // 20  (5 x 4, padded for float4)

    const int j0 = lane, j1 = lane + 64;

    // ---------------- M1: h1 = relu(x @ W1^T + b1), lane owns j0/j1 ----------------
    {
        const float* xr = x + b * 8;
        float4 xa = ((const float4*)xr)[0];
        float4 xb = ((const float4*)xr)[1];
        float4 wa0 = ((const float4*)(W1 + j0 * 8))[0];
        float4 wa1 = ((const float4*)(W1 + j0 * 8))[1];
        float4 wb0 = ((const float4*)(W1 + j1 * 8))[0];
        float4 wb1 = ((const float4*)(W1 + j1 * 8))[1];
        float h0 = b1[j0] + wa0.x*xa.x + wa0.y*xa.y + wa0.z*xa.z + wa0.w*xa.w
                          + wa1.x*xb.x + wa1.y*xb.y + wa1.z*xb.z + wa1.w*xb.w;
        float h1v = b1[j1] + wb0.x*xa.x + wb0.y*xa.y + wb0.z*xa.z + wb0.w*xa.w
                           + wb1.x*xb.x + wb1.y*xb.y + wb1.z*xb.z + wb1.w*xb.w;
        Lh1[j0] = fmaxf(h0, 0.f);
        Lh1[j1] = fmaxf(h1v, 0.f);
    }
    WSYNC();

    // ---------------- M2: h2 = relu(h1 @ W2^T + b2) ----------------
    float h2a, h2b;
    {
        float acc0 = b2[j0], acc1 = b2[j1];
        const float4* wra = (const float4*)(W2 + j0 * 128);
        const float4* wrb = (const float4*)(W2 + j1 * 128);
        const float4* hh  = (const float4*)Lh1;
        #pragma unroll 8
        for (int c4 = 0; c4 < 32; ++c4) {
            float4 h  = hh[c4];
            float4 wa = wra[c4];
            float4 wb = wrb[c4];
            acc0 += wa.x*h.x + wa.y*h.y + wa.z*h.z + wa.w*h.w;
            acc1 += wb.x*h.x + wb.y*h.y + wb.z*h.z + wb.w*h.w;
        }
        h2a = fmaxf(acc0, 0.f);
        h2b = fmaxf(acc1, 0.f);
    }

    // ---------------- M3: logits via butterfly (all lanes end up with lg[]) ----------------
    float lg[5];
    #pragma unroll
    for (int c = 0; c < 5; ++c) {
        float p = W3[c * 128 + j0] * h2a + W3[c * 128 + j1] * h2b;
        #pragma unroll
        for (int m = 32; m >= 1; m >>= 1) p += __shfl_xor(p, m, 64);
        lg[c] = p + b3[c];
    }

    // ---------------- softmax + cumsum -> knots (all lanes, redundant) ----------------
    float w4, w5, w6, w7;
    {
        float mx = lg[0];
        #pragma unroll
        for (int c = 1; c < 5; ++c) mx = fmaxf(mx, lg[c]);
        float e0 = expf(lg[0]-mx), e1 = expf(lg[1]-mx), e2 = expf(lg[2]-mx),
              e3 = expf(lg[3]-mx), e4 = expf(lg[4]-mx);
        float s = e0 + e1 + e2 + e3 + e4;
        float xs0 = e0 / s, xs1 = e1 / s, xs2 = e2 / s, xs3 = e3 / s;
        float c0 = xs0;
        float c1 = c0 + xs1;
        float c2 = c1 + xs2;
        float c3 = c2 + xs3;
        w4 = xs0 + (c0 - xs0);     // replicate ref's w = x4 + (cumsum - x4)
        w5 = xs1 + (c1 - xs1);
        w6 = xs2 + (c2 - xs2);
        w7 = xs3 + (c3 - xs3);
    }
    if (lane < 16) {
        float v;
        if (lane < 4)       v = 0.f;
        else if (lane == 4) v = w4;
        else if (lane == 5) v = w5;
        else if (lane == 6) v = w6;
        else if (lane == 7) v = w7;
        else                v = 1.f;
        Lkt[lane] = v;
        if (lane < 12) out_knots[b * 12 + lane] = v;
    }
    WSYNC();

    // ---------------- A build: basis rows 1..5 data-parallel (lane = r*10 + i) ----------------
    {
        const int r = lane / 10, i = lane - r * 10;
        if (lane < 50) {
            float t  = Lkt[r + 3];
            float k0 = Lkt[i],     k1 = Lkt[i + 1], k2 = Lkt[i + 2];
            float k3 = Lkt[i + 3], k4v = Lkt[i + 4];
            float N = (t >= k0 && t < k1) ? 1.f : 0.f;
            { // power = 1, m = 9
                float da = k1 - k0, db = k2 - k1;
                float a  = (da != 0.f) ? (t - k0) / da : 0.f;
                float bq = (db != 0.f) ? (k2 - t) / db : 0.f;
                float nb = __shfl_down(N, 1, 64);
                if (i < 9) N = N * a + nb * bq;
            }
            { // power = 2, m = 8
                float da = k2 - k0, db = k3 - k1;
                float a  = (da != 0.f) ? (t - k0) / da : 0.f;
                float bq = (db != 0.f) ? (k3 - t) / db : 0.f;
                float nb = __shfl_down(N, 1, 64);
                if (i < 8) N = N * a + nb * bq;
            }
            { // power = 3, m = 7
                float da = k3 - k0, db = k4v - k1;
                float a  = (da != 0.f) ? (t - k0) / da : 0.f;
                float bq = (db != 0.f) ? (k4v - t) / db : 0.f;
                float nb = __shfl_down(N, 1, 64);
                if (i < 7) N = N * a + nb * bq;
            }
            if (i < 8) LA[(r + 1) * 10 + i] = N;
        }
        // boundary rows 0, 6, 7 (knot values live in regs on every lane)
        if (lane < 24) {
            int rr  = lane >> 3;
            int row = (rr == 0) ? 0 : ((rr == 1) ? 6 : 7);
            int col = lane & 7;
            float v = 0.f;
            if (rr == 0) {
                if (col == 0)      v = w5;
                else if (col == 1) v = -w4 - w5;
                else if (col == 2) v = w4;
            } else if (rr == 1) {
                if (col == 7)      v = 1.f;
            } else {
                if (col == 5)      v = 1.f - w7;
                else if (col == 6) v = w7 + w6 - 2.f;
                else if (col == 7) v = 1.f - w6;
            }
            LA[row * 10 + col] = v;
        }
        if (lane < 12)
            LA[(1 + (lane >> 1)) * 10 + 8 + (lane & 1)] = P[b * 12 + lane];
        else if (lane < 16)
            LA[((lane < 14) ? 0 : 7) * 10 + 8 + (lane & 1)] = 0.f;
    }
    WSYNC();

    // ---------------- GE with partial pivoting: lanes 0..7 hold rows ----------------
    if (lane < 8) {
        float a[10];
        #pragma unroll
        for (int c = 0; c < 10; ++c) a[c] = LA[lane * 10 + c];
        int done = 0, pcol = 7;
        #pragma unroll
        for (int col = 0; col < 8; ++col) {
            float bv = done ? -1.f : fabsf(a[col]);
            int bi = lane;
            #pragma unroll
            for (int m = 1; m <= 4; m <<= 1) {
                float ov = __shfl_xor(bv, m, 64);
                int   oi = __shfl_xor(bi, m, 64);
                if (ov > bv || (ov == bv && oi < bi)) { bv = ov; bi = oi; }
            }
            float pr[10];
            #pragma unroll
            for (int c = 0; c < 10; ++c) pr[c] = __shfl(a[c], bi, 64);
            if (lane == bi) { done = 1; pcol = col; }
            else if (!done) {
                float f = a[col] / pr[col];
                #pragma unroll
                for (int c = 0; c < 10; ++c) if (c > col) a[c] -= f * pr[c];
            }
        }
        #pragma unroll
        for (int c = 0; c < 10; ++c) LA[pcol * 10 + c] = a[c];
    }
    WSYNC();

    // ---------------- back-substitution: all lanes, parity-redundant (even=x, odd=y) ----------------
    {
        const int par = lane & 1;
        float C[8];
        #pragma unroll
        for (int col = 7; col >= 0; --col) {
            float s = LA[col * 10 + 8 + par];
            #pragma unroll
            for (int c = col + 1; c < 8; ++c) s -= LA[col * 10 + c] * C[c];
            C[col] = s / LA[col * 10 + col];
        }
        // Q and R control points; denominators kt[4+i]-kt[1+i] and kt[4+i]-kt[2+i]
        float Qr[7], Rr[6];
        const float dq[7] = { w4, w5, w6, w7 - w4, 1.f - w5, 1.f - w6, 1.f - w7 };
        #pragma unroll
        for (int i = 0; i < 7; ++i) Qr[i] = (3.f / dq[i]) * (C[i + 1] - C[i]);
        const float dr[6] = { w4, w5, w6 - w4, w7 - w5, 1.f - w6, 1.f - w7 };
        #pragma unroll
        for (int i = 0; i < 6; ++i) Rr[i] = (2.f / dr[i]) * (Qr[i + 1] - Qr[i]);
        if (lane < 2) {
            #pragma unroll
            for (int i = 0; i < 7; ++i) LQ[i * 2 + par] = Qr[i];
            #pragma unroll
            for (int i = 0; i < 6; ++i) LR[i * 2 + par] = Rr[i];
        }
    }
    // per-segment reciprocal table (lanes 0..4)
    if (lane < 5) {
        const int k = lane;
        float k2v = Lkt[2 + k], k3v = Lkt[3 + k], k4v = Lkt[4 + k], k5v = Lkt[5 + k];
        float4 rv;
        rv.x = 1.f / (k4v - k2v);
        rv.y = 1.f / (k5v - k3v);
        rv.z = 1.f / (k4v - k3v);
        rv.w = 0.f;
        ((float4*)Lrcp)[k] = rv;
    }
    WSYNC();

    // ---------------- evaluate 1000 points, divide-free ----------------
    {
        const float c999 = 1.f / 999.f;
        float acc = 0.f;
        #pragma unroll 4
        for (int it = 0; it < 16; ++it) {
            int idx = lane + (it << 6);
            if (idx < NPTS) {
                float t = (float)idx * c999;
                int k = (t > w4) + (t > w5) + (t > w6) + (t > w7);
                float k2 = Lkt[2 + k], k3 = Lkt[3 + k];
                float k4 = Lkt[4 + k], k5 = Lkt[5 + k];
                float4 rv = ((const float4*)Lrcp)[k];
                float2 q0 = ((const float2*)LQ)[k];
                float2 q1 = ((const float2*)LQ)[k + 1];
                float2 q2 = ((const float2*)LQ)[k + 2];
                float2 r0 = ((const float2*)LR)[k];
                float2 r1 = ((const float2*)LR)[k + 1];
                float d4 = k4 - t, d2 = t - k2, d3 = t - k3, d5 = k5 - t;
                float f0x = (d4 * q0.x + d2 * q1.x) * rv.x;
                float f0y = (d4 * q0.y + d2 * q1.y) * rv.x;
                float f1x = (d5 * q1.x + d3 * q2.x) * rv.y;
                float f1y = (d5 * q1.y + d3 * q2.y) * rv.y;
                float spx = (d4 * f0x + d3 * f1x) * rv.z;
                float spy = (d4 * f0y + d3 * f1y) * rv.z;
                float sdx = (d4 * r0.x + d3 * r1.x) * rv.z;
                float sdy = (d4 * r0.y + d3 * r1.y) * rv.z;
                float s2 = spx * spx + spy * spy;
                float cross = spx * sdy - spy * sdx;
                float rs = rsqrtf(s2);
                float rs2 = rs * rs;
                float val = cross * cross * (rs2 * rs2 * rs);
                acc += ((idx & 1) ? 4.f : 2.f) * val;
            }
        }
        #pragma unroll
        for (int m = 32; m >= 1; m >>= 1) acc += __shfl_xor(acc, m, 64);
        if (lane == 0) out_integ[b] = (1.f / 999.f) / 3.f * acc;
    }
}

extern "C" void kernel_launch(void* const* d_in, const int* in_sizes, int n_in,
                              void* d_out, int out_size, void* d_ws, size_t ws_size,
                              hipStream_t stream) {
    const float* x  = (const float*)d_in[0];
    const float* P  = (const float*)d_in[1];
    const float* W1 = (const float*)d_in[2];
    const float* b1 = (const float*)d_in[3];
    const float* W2 = (const float*)d_in[4];
    const float* b2 = (const float*)d_in[5];
    const float* W3 = (const float*)d_in[6];
    const float* b3 = (const float*)d_in[7];
    float* out_integ = (float*)d_out;
    float* out_knots = out_integ + BATCH;

    dim3 grid(BATCH / 4), block(256);
    net2_wave<<<grid, block, 0, stream>>>(x, P, W1, b1, W2, b2, W3, b3,
                                          out_integ, out_knots);
}

// Round 5
// 45.668 us; speedup vs baseline: 1.0888x; 1.0888x over previous
//
#include <hip/hip_runtime.h>
#include <math.h>

#define BATCH 4096
#define NPTS 1000

// Within-wave LDS producer->consumer fence (LDS ops are memory ops; the
// clobber orders them, sched_barrier stops migration).
#define WSYNC() do { asm volatile("s_waitcnt lgkmcnt(0)" ::: "memory"); \
                     __builtin_amdgcn_sched_barrier(0); } while (0)

// per-element LDS region (floats): kt 16 | A 8x10 | Q 16 | R 16 | coef 5x12+pad
#define EREG 192
#define OFF_KT 0
#define OFF_A  16
#define OFF_Q  96
#define OFF_R  112
#define OFF_CF 128

__global__ __launch_bounds__(256, 8) void net2_fused(
    const float* __restrict__ x,   // (B,8)
    const float* __restrict__ P,   // (B,6,2,1)
    const float* __restrict__ W1,  // (128,8)
    const float* __restrict__ b1,  // (128)
    const float* __restrict__ W2,  // (128,128)
    const float* __restrict__ b2,  // (128)
    const float* __restrict__ W3,  // (5,128)
    const float* __restrict__ b3,  // (5)
    float* __restrict__ out_integ, // (B)
    float* __restrict__ out_knots) // (B,12)
{
    __shared__ float s_h1[2][128];
    __shared__ float s_part[4][8];
    __shared__ float s_er[2][EREG];
    __shared__ float s_p[4];

    const int tid  = threadIdx.x;
    const int wv   = tid >> 6;
    const int lane = tid & 63;
    const int b0   = blockIdx.x * 2;
    const int elem = tid >> 7;          // element this thread serves in MLP
    const int row  = tid & 127;         // h-dimension it owns

    // ---------------- M1: h1 = relu(x @ W1^T + b1) ----------------
    {
        const float* xr = x + (b0 + elem) * 8;
        float4 xa = ((const float4*)xr)[0];
        float4 xb = ((const float4*)xr)[1];
        float4 w0 = ((const float4*)(W1 + row * 8))[0];
        float4 w1 = ((const float4*)(W1 + row * 8))[1];
        float h = b1[row] + w0.x*xa.x + w0.y*xa.y + w0.z*xa.z + w0.w*xa.w
                          + w1.x*xb.x + w1.y*xb.y + w1.z*xb.z + w1.w*xb.w;
        s_h1[elem][row] = fmaxf(h, 0.f);
    }
    __syncthreads();

    // ---------------- M2: h2[row] for own element ----------------
    float h2;
    {
        float acc = b2[row];
        const float4* wr = (const float4*)(W2 + row * 128);
        const float4* hh = (const float4*)s_h1[elem];
        #pragma unroll 8
        for (int c4 = 0; c4 < 32; ++c4) {
            float4 w = wr[c4];
            float4 h = hh[c4];
            acc += w.x*h.x + w.y*h.y + w.z*h.z + w.w*h.w;
        }
        h2 = fmaxf(acc, 0.f);
    }

    // ---------------- M3: per-wave logit partials ----------------
    #pragma unroll
    for (int c = 0; c < 5; ++c) {
        float p = W3[c * 128 + row] * h2;
        #pragma unroll
        for (int m = 32; m >= 1; m >>= 1) p += __shfl_xor(p, m, 64);
        if (lane == 0) s_part[wv][c] = p;
    }
    __syncthreads();

    // ---------------- prep: one wave per element ----------------
    if ((wv & 1) == 0) {
        const int e = wv >> 1;
        float* E = s_er[e];
        float* LA = E + OFF_A;

        float lg[5];
        #pragma unroll
        for (int c = 0; c < 5; ++c) lg[c] = s_part[2*e][c] + s_part[2*e+1][c] + b3[c];

        // softmax + cumsum -> knots (all lanes redundant, regs)
        float w4, w5, w6, w7;
        {
            float mx = lg[0];
            #pragma unroll
            for (int c = 1; c < 5; ++c) mx = fmaxf(mx, lg[c]);
            float e0 = expf(lg[0]-mx), e1 = expf(lg[1]-mx), e2 = expf(lg[2]-mx),
                  e3 = expf(lg[3]-mx), e4 = expf(lg[4]-mx);
            float s = e0 + e1 + e2 + e3 + e4;
            float xs0 = e0/s, xs1 = e1/s, xs2 = e2/s, xs3 = e3/s;
            float c0 = xs0;
            float c1 = c0 + xs1;
            float c2 = c1 + xs2;
            float c3 = c2 + xs3;
            w4 = xs0 + (c0 - xs0);   // replicate ref rounding
            w5 = xs1 + (c1 - xs1);
            w6 = xs2 + (c2 - xs2);
            w7 = xs3 + (c3 - xs3);
        }
        if (lane < 16) {
            float v;
            if (lane < 4)       v = 0.f;
            else if (lane == 4) v = w4;
            else if (lane == 5) v = w5;
            else if (lane == 6) v = w6;
            else if (lane == 7) v = w7;
            else                v = 1.f;
            E[OFF_KT + lane] = v;
            if (lane < 12) out_knots[(b0 + e) * 12 + lane] = v;
        }
        WSYNC();

        // A build: basis rows 1..5 data-parallel (lane = r*10 + i)
        {
            const int r = lane / 10, i = lane - r * 10;
            if (lane < 50) {
                float t  = E[OFF_KT + r + 3];
                float k0 = E[OFF_KT + i],     k1 = E[OFF_KT + i + 1], k2 = E[OFF_KT + i + 2];
                float k3 = E[OFF_KT + i + 3], k4v = E[OFF_KT + i + 4];
                float N = (t >= k0 && t < k1) ? 1.f : 0.f;
                { // power = 1, m = 9
                    float da = k1 - k0, db = k2 - k1;
                    float a  = (da != 0.f) ? (t - k0) / da : 0.f;
                    float bq = (db != 0.f) ? (k2 - t) / db : 0.f;
                    float nb = __shfl_down(N, 1, 64);
                    if (i < 9) N = N * a + nb * bq;
                }
                { // power = 2, m = 8
                    float da = k2 - k0, db = k3 - k1;
                    float a  = (da != 0.f) ? (t - k0) / da : 0.f;
                    float bq = (db != 0.f) ? (k3 - t) / db : 0.f;
                    float nb = __shfl_down(N, 1, 64);
                    if (i < 8) N = N * a + nb * bq;
                }
                { // power = 3, m = 7
                    float da = k3 - k0, db = k4v - k1;
                    float a  = (da != 0.f) ? (t - k0) / da : 0.f;
                    float bq = (db != 0.f) ? (k4v - t) / db : 0.f;
                    float nb = __shfl_down(N, 1, 64);
                    if (i < 7) N = N * a + nb * bq;
                }
                if (i < 8) LA[(r + 1) * 10 + i] = N;
            }
            if (lane < 24) {   // boundary rows 0, 6, 7
                int rr  = lane >> 3;
                int rw  = (rr == 0) ? 0 : ((rr == 1) ? 6 : 7);
                int col = lane & 7;
                float v = 0.f;
                if (rr == 0) {
                    if (col == 0)      v = w5;
                    else if (col == 1) v = -w4 - w5;
                    else if (col == 2) v = w4;
                } else if (rr == 1) {
                    if (col == 7)      v = 1.f;
                } else {
                    if (col == 5)      v = 1.f - w7;
                    else if (col == 6) v = w7 + w6 - 2.f;
                    else if (col == 7) v = 1.f - w6;
                }
                LA[rw * 10 + col] = v;
            }
            if (lane < 12)
                LA[(1 + (lane >> 1)) * 10 + 8 + (lane & 1)] = P[(b0 + e) * 12 + lane];
            else if (lane < 16)
                LA[((lane < 14) ? 0 : 7) * 10 + 8 + (lane & 1)] = 0.f;
        }
        WSYNC();

        // GE with partial pivoting: lanes 0..7 hold rows (proven round-3 path)
        if (lane < 8) {
            float a[10];
            #pragma unroll
            for (int c = 0; c < 10; ++c) a[c] = LA[lane * 10 + c];
            int done = 0, pcol = 7;
            #pragma unroll
            for (int col = 0; col < 8; ++col) {
                float bv = done ? -1.f : fabsf(a[col]);
                int bi = lane;
                #pragma unroll
                for (int m = 1; m <= 4; m <<= 1) {
                    float ov = __shfl_xor(bv, m, 64);
                    int   oi = __shfl_xor(bi, m, 64);
                    if (ov > bv || (ov == bv && oi < bi)) { bv = ov; bi = oi; }
                }
                float pr[10];
                #pragma unroll
                for (int c = 0; c < 10; ++c) pr[c] = __shfl(a[c], bi, 64);
                if (lane == bi) { done = 1; pcol = col; }
                else if (!done) {
                    float f = a[col] / pr[col];
                    #pragma unroll
                    for (int c = 0; c < 10; ++c) if (c > col) a[c] -= f * pr[c];
                }
            }
            #pragma unroll
            for (int c = 0; c < 10; ++c) LA[pcol * 10 + c] = a[c];
        }
        WSYNC();

        // back-substitution (all lanes, parity-redundant) + Q/R -> LDS
        {
            const int par = lane & 1;
            float C[8];
            #pragma unroll
            for (int col = 7; col >= 0; --col) {
                float s = LA[col * 10 + 8 + par];
                #pragma unroll
                for (int c = col + 1; c < 8; ++c) s -= LA[col * 10 + c] * C[c];
                C[col] = s / LA[col * 10 + col];
            }
            float Qr[7], Rr[6];
            const float dq[7] = { w4, w5, w6, w7 - w4, 1.f - w5, 1.f - w6, 1.f - w7 };
            #pragma unroll
            for (int i = 0; i < 7; ++i) Qr[i] = (3.f / dq[i]) * (C[i + 1] - C[i]);
            const float dr[6] = { w4, w5, w6 - w4, w7 - w5, 1.f - w6, 1.f - w7 };
            #pragma unroll
            for (int i = 0; i < 6; ++i) Rr[i] = (2.f / dr[i]) * (Qr[i + 1] - Qr[i]);
            if (lane < 2) {
                #pragma unroll
                for (int i = 0; i < 7; ++i) E[OFF_Q + i * 2 + par] = Qr[i];
                #pragma unroll
                for (int i = 0; i < 6; ++i) E[OFF_R + i * 2 + par] = Rr[i];
            }
        }
        WSYNC();

        // per-segment polynomial coefficients: lane = s*2 + par, s in [0,5)
        if (lane < 10) {
            const int s5 = lane >> 1, par = lane & 1;
            float k2 = E[OFF_KT + 2 + s5], k3 = E[OFF_KT + 3 + s5];
            float k4 = E[OFF_KT + 4 + s5], k5 = E[OFF_KT + 5 + s5];
            float q0 = E[OFF_Q + s5 * 2 + par];
            float q1 = E[OFF_Q + (s5 + 1) * 2 + par];
            float q2 = E[OFF_Q + (s5 + 2) * 2 + par];
            float r0 = E[OFF_R + s5 * 2 + par];
            float r1 = E[OFF_R + (s5 + 1) * 2 + par];
            float r42 = 1.f / (k4 - k2), r53 = 1.f / (k5 - k3), r43 = 1.f / (k4 - k3);
            // f0 = A0 + B0 t ; f1 = A1 + B1 t ; sp = c0 + c1 t + c2 t^2 ; sd = e0 + e1 t
            float A0 = (k4 * q0 - k2 * q1) * r42, B0 = (q1 - q0) * r42;
            float A1 = (k5 * q1 - k3 * q2) * r53, B1 = (q2 - q1) * r53;
            float c0 = r43 * (k4 * A0 - k3 * A1);
            float c1 = r43 * (k4 * B0 - A0 + A1 - k3 * B1);
            float c2 = r43 * (B1 - B0);
            float e0 = r43 * (k4 * r0 - k3 * r1);
            float e1 = r43 * (r1 - r0);
            const int base = OFF_CF + s5 * 12;
            E[base + par * 3 + 0] = c0;     // [cx0 cx1 cx2 cy0 cy1 cy2 ...]
            E[base + par * 3 + 1] = c1;
            E[base + par * 3 + 2] = c2;
            E[base + 6 + par * 2 + 0] = e0; // [... ex0 ex1 ey0 ey1 pad pad]
            E[base + 6 + par * 2 + 1] = e1;
        }
        WSYNC();
    }
    __syncthreads();

    // ---------------- eval: 2 waves per element, 500 points each ----------------
    {
        const int e = wv >> 1, half = wv & 1;
        const float* E = s_er[e];
        const float w4 = E[OFF_KT + 4], w5 = E[OFF_KT + 5];
        const float w6 = E[OFF_KT + 6], w7 = E[OFF_KT + 7];
        const float c999 = 1.f / 999.f;
        float acc = 0.f;
        #pragma unroll 4
        for (int it = 0; it < 8; ++it) {
            int idx = half * 64 + lane + it * 128;
            if (idx < NPTS) {
                float t = (float)idx * c999;
                int k = (t > w4) + (t > w5) + (t > w6) + (t > w7);
                const float* cf = E + OFF_CF + k * 12;
                float4 ca = *(const float4*)cf;        // cx0 cx1 cx2 cy0
                float4 cb = *(const float4*)(cf + 4);  // cy1 cy2 ex0 ex1
                float2 cc = *(const float2*)(cf + 8);  // ey0 ey1
                float spx = (ca.z * t + ca.y) * t + ca.x;
                float spy = (cb.y * t + cb.x) * t + ca.w;
                float sdx = cb.w * t + cb.z;
                float sdy = cc.y * t + cc.x;
                float s2 = spx * spx + spy * spy;
                float cross = spx * sdy - spy * sdx;
                float rs = rsqrtf(s2);
                float rs2 = rs * rs;
                float val = cross * cross * (rs2 * rs2 * rs);
                acc += ((idx & 1) ? 4.f : 2.f) * val;
            }
        }
        #pragma unroll
        for (int m = 32; m >= 1; m >>= 1) acc += __shfl_xor(acc, m, 64);
        if (lane == 0) s_p[wv] = acc;
    }
    __syncthreads();
    if (tid < 2)
        out_integ[b0 + tid] = (1.f / 999.f) / 3.f * (s_p[2 * tid] + s_p[2 * tid + 1]);
}

extern "C" void kernel_launch(void* const* d_in, const int* in_sizes, int n_in,
                              void* d_out, int out_size, void* d_ws, size_t ws_size,
                              hipStream_t stream) {
    const float* x  = (const float*)d_in[0];
    const float* P  = (const float*)d_in[1];
    const float* W1 = (const float*)d_in[2];
    const float* b1 = (const float*)d_in[3];
    const float* W2 = (const float*)d_in[4];
    const float* b2 = (const float*)d_in[5];
    const float* W3 = (const float*)d_in[6];
    const float* b3 = (const float*)d_in[7];
    float* out_integ = (float*)d_out;
    float* out_knots = out_integ + BATCH;

    dim3 grid(BATCH / 2), block(256);
    net2_fused<<<grid, block, 0, stream>>>(x, P, W1, b1, W2, b2, W3, b3,
                                           out_integ, out_knots);
}

// Round 6
// 33.059 us; speedup vs baseline: 1.5040x; 1.3814x over previous
//
#include <hip/hip_runtime.h>
#include <math.h>

#define BATCH 4096
#define NPTS 1000

// Within-wave LDS producer->consumer fence (LDS ops are memory ops; the
// clobber orders them, sched_barrier stops migration).
#define WSYNC() do { asm volatile("s_waitcnt lgkmcnt(0)" ::: "memory"); \
                     __builtin_amdgcn_sched_barrier(0); } while (0)

// ============================ K1: MLP -> logits ============================
// 8 elements/block; thread = (half p, row). W2 L2 traffic = 64KB per 2 waves.
__global__ __launch_bounds__(256) void k1_mlp(
    const float* __restrict__ x, const float* __restrict__ W1,
    const float* __restrict__ b1, const float* __restrict__ W2,
    const float* __restrict__ b2, const float* __restrict__ W3,
    const float* __restrict__ b3, float* __restrict__ logits)
{
    __shared__ float s_h1[8][128];
    __shared__ float s_part[4][4][5];
    const int tid = threadIdx.x;
    const int wv = tid >> 6, lane = tid & 63;
    const int p = tid >> 7, row = tid & 127;
    const int b0 = blockIdx.x * 8;

    // M1: h1 rows for 4 elements
    {
        float4 w0 = ((const float4*)(W1 + row * 8))[0];
        float4 w1 = ((const float4*)(W1 + row * 8))[1];
        float bb = b1[row];
        #pragma unroll
        for (int k = 0; k < 4; ++k) {
            const float* xr = x + (b0 + p * 4 + k) * 8;
            float4 xa = ((const float4*)xr)[0];
            float4 xb = ((const float4*)xr)[1];
            float h = bb + w0.x*xa.x + w0.y*xa.y + w0.z*xa.z + w0.w*xa.w
                         + w1.x*xb.x + w1.y*xb.y + w1.z*xb.z + w1.w*xb.w;
            s_h1[p * 4 + k][row] = fmaxf(h, 0.f);
        }
    }
    __syncthreads();

    // M2: h2[row] for 4 elements (4 independent FMA chains)
    float bb2 = b2[row];
    float a0 = bb2, a1 = bb2, a2 = bb2, a3 = bb2;
    {
        const float4* wr = (const float4*)(W2 + row * 128);
        const float4* h0 = (const float4*)s_h1[p * 4 + 0];
        const float4* h1 = (const float4*)s_h1[p * 4 + 1];
        const float4* h2p = (const float4*)s_h1[p * 4 + 2];
        const float4* h3 = (const float4*)s_h1[p * 4 + 3];
        #pragma unroll 8
        for (int c4 = 0; c4 < 32; ++c4) {
            float4 w = wr[c4];
            float4 ha = h0[c4], hb = h1[c4], hc = h2p[c4], hd = h3[c4];
            a0 += w.x*ha.x + w.y*ha.y + w.z*ha.z + w.w*ha.w;
            a1 += w.x*hb.x + w.y*hb.y + w.z*hb.z + w.w*hb.w;
            a2 += w.x*hc.x + w.y*hc.y + w.z*hc.z + w.w*hc.w;
            a3 += w.x*hd.x + w.y*hd.y + w.z*hd.z + w.w*hd.w;
        }
    }
    float h2_0 = fmaxf(a0, 0.f), h2_1 = fmaxf(a1, 0.f);
    float h2_2 = fmaxf(a2, 0.f), h2_3 = fmaxf(a3, 0.f);

    // M3: logit partials via butterflies
    #pragma unroll
    for (int c = 0; c < 5; ++c) {
        float wc = W3[c * 128 + row];
        float p0 = wc * h2_0, p1 = wc * h2_1, p2 = wc * h2_2, p3 = wc * h2_3;
        #pragma unroll
        for (int m = 32; m >= 1; m >>= 1) {
            p0 += __shfl_xor(p0, m, 64);
            p1 += __shfl_xor(p1, m, 64);
            p2 += __shfl_xor(p2, m, 64);
            p3 += __shfl_xor(p3, m, 64);
        }
        if (lane == 0) {
            s_part[wv][0][c] = p0; s_part[wv][1][c] = p1;
            s_part[wv][2][c] = p2; s_part[wv][3][c] = p3;
        }
    }
    __syncthreads();
    if (tid < 40) {
        int e = tid / 5, c = tid % 5;
        int pw = (e >> 2) * 2;
        logits[(b0 + e) * 8 + c] =
            s_part[pw][e & 3][c] + s_part[pw + 1][e & 3][c] + b3[c];
    }
}

// ============================ K2: prep =====================================
// 1 wave = 8 elements (groups of 8 lanes). Per-lane register A-row build,
// proven shfl-GE, round-4-verbatim backsub/Q/R/coeffs.
__global__ __launch_bounds__(64) void k2_prep(
    const float* __restrict__ P, const float* __restrict__ logits,
    float* __restrict__ coef, float* __restrict__ out_knots)
{
    __shared__ float LA[8][8][10];
    __shared__ float LQ[8][16];
    __shared__ float LR[8][16];
    const int lane = threadIdx.x;
    const int el = lane >> 3, r = lane & 7;
    const int e = blockIdx.x * 8 + el;

    // softmax + cumsum -> knot spans (round-4 numerics, per-lane redundant)
    float lg0 = logits[e*8+0], lg1 = logits[e*8+1], lg2 = logits[e*8+2],
          lg3 = logits[e*8+3], lg4 = logits[e*8+4];
    float mx = fmaxf(fmaxf(fmaxf(fmaxf(lg0, lg1), lg2), lg3), lg4);
    float e0 = expf(lg0-mx), e1 = expf(lg1-mx), e2 = expf(lg2-mx),
          e3 = expf(lg3-mx), e4 = expf(lg4-mx);
    float s = e0 + e1 + e2 + e3 + e4;
    float xs0 = e0/s, xs1 = e1/s, xs2 = e2/s, xs3 = e3/s;
    float c0 = xs0, c1 = c0 + xs1, c2 = c1 + xs2, c3 = c2 + xs3;
    float w4 = xs0 + (c0 - xs0);
    float w5 = xs1 + (c1 - xs1);
    float w6 = xs2 + (c2 - xs2);
    float w7 = xs3 + (c3 - xs3);

    // knots output + w-span stash for K3
    {
        float kv = (r < 4) ? 0.f : (r == 4 ? w4 : r == 5 ? w5 : r == 6 ? w6 : w7);
        out_knots[e * 12 + r] = kv;
        if (r < 4) {
            out_knots[e * 12 + 8 + r] = 1.f;
            coef[e * 64 + 60 + r] = (r == 0 ? w4 : r == 1 ? w5 : r == 2 ? w6 : w7);
        }
    }

    // basis row recurrence per lane (rows 1..5), static-indexed, exact div
    const float ka[12] = {0.f,0.f,0.f,0.f,w4,w5,w6,w7,1.f,1.f,1.f,1.f};
    float t = (r == 2) ? w4 : (r == 3) ? w5 : (r == 4) ? w6 : (r == 5) ? w7 : 0.f;
    float N[11];
    #pragma unroll
    for (int i = 0; i < 11; ++i)
        N[i] = (t >= ka[i] && t < ka[i+1]) ? 1.f : 0.f;
    #pragma unroll
    for (int pw = 1; pw <= 3; ++pw) {
        #pragma unroll
        for (int i = 0; i < 10; ++i) {
            if (i < 10 - pw) {   // m = 10-pw, replicates ref's partial update
                float da = ka[i+pw] - ka[i];
                float av = (da != 0.f) ? (t - ka[i]) / da : 0.f;
                float db = ka[i+pw+1] - ka[i+1];
                float bv = (db != 0.f) ? (ka[i+pw+1] - t) / db : 0.f;
                N[i] = N[i] * av + N[i+1] * bv;
            }
        }
    }

    // assemble this lane's A row + rhs in registers
    float a[10];
    #pragma unroll
    for (int c = 0; c < 8; ++c) {
        float v0 = (c==0) ? w5 : (c==1) ? (-w4-w5) : (c==2) ? w4 : 0.f;
        float v6 = (c==7) ? 1.f : 0.f;
        float v7 = (c==5) ? (1.f-w7) : (c==6) ? (w7+w6-2.f) : (c==7) ? (1.f-w6) : 0.f;
        float vb = (r==0) ? v0 : (r==6) ? v6 : v7;
        a[c] = (r >= 1 && r <= 5) ? N[c] : vb;
    }
    {
        float px = 0.f, py = 0.f;
        if (r >= 1 && r <= 6) {
            px = P[e * 12 + (r-1) * 2 + 0];
            py = P[e * 12 + (r-1) * 2 + 1];
        }
        a[8] = px; a[9] = py;
    }

    // GE with partial pivoting: 8-lane groups, proven shfl path
    int done = 0, pcol = 7;
    #pragma unroll
    for (int col = 0; col < 8; ++col) {
        float bv = done ? -1.f : fabsf(a[col]);
        int bi = lane;
        #pragma unroll
        for (int m = 1; m <= 4; m <<= 1) {
            float ov = __shfl_xor(bv, m, 64);
            int   oi = __shfl_xor(bi, m, 64);
            if (ov > bv || (ov == bv && oi < bi)) { bv = ov; bi = oi; }
        }
        float pr[10];
        #pragma unroll
        for (int c = 0; c < 10; ++c) pr[c] = __shfl(a[c], bi, 64);
        if (lane == bi) { done = 1; pcol = col; }
        else if (!done) {
            float f = a[col] / pr[col];
            #pragma unroll
            for (int c = 0; c < 10; ++c) if (c > col) a[c] -= f * pr[c];
        }
    }
    #pragma unroll
    for (int c = 0; c < 10; ++c) LA[el][pcol][c] = a[c];
    WSYNC();

    // back-substitution (parity lanes 0/1 per group) + Q/R
    if (r < 2) {
        const int par = r;
        float C[8];
        #pragma unroll
        for (int col = 7; col >= 0; --col) {
            float sv = LA[el][col][8 + par];
            #pragma unroll
            for (int c = col + 1; c < 8; ++c) sv -= LA[el][col][c] * C[c];
            C[col] = sv / LA[el][col][col];
        }
        float Qr[7], Rr[6];
        const float dq[7] = { w4, w5, w6, w7 - w4, 1.f - w5, 1.f - w6, 1.f - w7 };
        #pragma unroll
        for (int i = 0; i < 7; ++i) Qr[i] = (3.f / dq[i]) * (C[i+1] - C[i]);
        const float dr[6] = { w4, w5, w6 - w4, w7 - w5, 1.f - w6, 1.f - w7 };
        #pragma unroll
        for (int i = 0; i < 6; ++i) Rr[i] = (2.f / dr[i]) * (Qr[i+1] - Qr[i]);
        #pragma unroll
        for (int i = 0; i < 7; ++i) LQ[el][i*2+par] = Qr[i];
        #pragma unroll
        for (int i = 0; i < 6; ++i) LR[el][i*2+par] = Rr[i];
    }
    WSYNC();

    // per-segment polynomial coeffs (round-4 formulas), lane r<5 = segment
    if (r < 5) {
        const int s5 = r;
        float k2 = (s5 <= 1) ? 0.f : (s5 == 2) ? w4 : (s5 == 3) ? w5 : w6;  // ka[2+s]
        float k3 = (s5 == 0) ? 0.f : (s5 == 1) ? w4 : (s5 == 2) ? w5 : (s5 == 3) ? w6 : w7;
        float k4 = (s5 == 0) ? w4 : (s5 == 1) ? w5 : (s5 == 2) ? w6 : (s5 == 3) ? w7 : 1.f;
        float k5 = (s5 == 0) ? w5 : (s5 == 1) ? w6 : (s5 == 2) ? w7 : 1.f;
        float q0x = LQ[el][s5*2],     q0y = LQ[el][s5*2+1];
        float q1x = LQ[el][(s5+1)*2], q1y = LQ[el][(s5+1)*2+1];
        float q2x = LQ[el][(s5+2)*2], q2y = LQ[el][(s5+2)*2+1];
        float r0x = LR[el][s5*2],     r0y = LR[el][s5*2+1];
        float r1x = LR[el][(s5+1)*2], r1y = LR[el][(s5+1)*2+1];
        float r42 = 1.f/(k4-k2), r53 = 1.f/(k5-k3), r43 = 1.f/(k4-k3);
        float A0x = (k4*q0x - k2*q1x)*r42, B0x = (q1x-q0x)*r42;
        float A1x = (k5*q1x - k3*q2x)*r53, B1x = (q2x-q1x)*r53;
        float c0x = r43*(k4*A0x - k3*A1x);
        float c1x = r43*(k4*B0x - A0x + A1x - k3*B1x);
        float c2x = r43*(B1x - B0x);
        float e0x = r43*(k4*r0x - k3*r1x);
        float e1x = r43*(r1x - r0x);
        float A0y = (k4*q0y - k2*q1y)*r42, B0y = (q1y-q0y)*r42;
        float A1y = (k5*q1y - k3*q2y)*r53, B1y = (q2y-q1y)*r53;
        float c0y = r43*(k4*A0y - k3*A1y);
        float c1y = r43*(k4*B0y - A0y + A1y - k3*B1y);
        float c2y = r43*(B1y - B0y);
        float e0y = r43*(k4*r0y - k3*r1y);
        float e1y = r43*(r1y - r0y);
        float* cb = coef + e * 64 + s5 * 12;
        cb[0] = c0x; cb[1] = c1x; cb[2]  = c2x; cb[3]  = c0y;
        cb[4] = c1y; cb[5] = c2y; cb[6]  = e0x; cb[7]  = e1x;
        cb[8] = e0y; cb[9] = e1y; cb[10] = 0.f; cb[11] = 0.f;
    }
}

// ============================ K3: eval =====================================
// 1 wave = 1 element. Segment-ordered loop; coeffs hoisted to scalars via
// readlane; inner loop is pure VALU (no LDS, no divergence).
__global__ __launch_bounds__(256) void k3_eval(
    const float* __restrict__ coef, float* __restrict__ out_integ)
{
    const int tid = threadIdx.x, wv = tid >> 6, lane = tid & 63;
    const int e = blockIdx.x * 4 + wv;
    const float c999 = 1.f / 999.f;

    float v = coef[e * 64 + lane];
    int vi = __float_as_int(v);
    float w4 = __int_as_float(__builtin_amdgcn_readlane(vi, 60));
    float w5 = __int_as_float(__builtin_amdgcn_readlane(vi, 61));
    float w6 = __int_as_float(__builtin_amdgcn_readlane(vi, 62));
    float w7 = __int_as_float(__builtin_amdgcn_readlane(vi, 63));

    // first idx with idx*c999 > w  (exact same predicate as ref's k-count)
    auto bsearch = [&](float w) {
        int lo = 0, hi = 1000;
        #pragma unroll
        for (int it = 0; it < 10; ++it) {
            int mid = (lo + hi) >> 1;
            bool pr = ((float)mid * c999 > w);
            hi = pr ? mid : hi;
            lo = pr ? lo : (mid + 1);
        }
        return lo;
    };
    int B0 = bsearch(w4), B1 = bsearch(w5), B2 = bsearch(w6), B3 = bsearch(w7);

    float acc = 0.f;
    #define DOSEG(S, LOE, HIE) { \
        float cx0 = __int_as_float(__builtin_amdgcn_readlane(vi, (S)*12+0)); \
        float cx1 = __int_as_float(__builtin_amdgcn_readlane(vi, (S)*12+1)); \
        float cx2 = __int_as_float(__builtin_amdgcn_readlane(vi, (S)*12+2)); \
        float cy0 = __int_as_float(__builtin_amdgcn_readlane(vi, (S)*12+3)); \
        float cy1 = __int_as_float(__builtin_amdgcn_readlane(vi, (S)*12+4)); \
        float cy2 = __int_as_float(__builtin_amdgcn_readlane(vi, (S)*12+5)); \
        float ex0 = __int_as_float(__builtin_amdgcn_readlane(vi, (S)*12+6)); \
        float ex1 = __int_as_float(__builtin_amdgcn_readlane(vi, (S)*12+7)); \
        float ey0 = __int_as_float(__builtin_amdgcn_readlane(vi, (S)*12+8)); \
        float ey1 = __int_as_float(__builtin_amdgcn_readlane(vi, (S)*12+9)); \
        int lo = (LOE), hi = (HIE); \
        float wl = ((lo + lane) & 1) ? 4.f : 2.f; \
        for (int idx = lo + lane; idx < hi; idx += 64) { \
            float tt = (float)idx * c999; \
            float spx = (cx2 * tt + cx1) * tt + cx0; \
            float spy = (cy2 * tt + cy1) * tt + cy0; \
            float sdx = ex1 * tt + ex0; \
            float sdy = ey1 * tt + ey0; \
            float s2 = spx * spx + spy * spy; \
            float cross = spx * sdy - spy * sdx; \
            float rs = rsqrtf(s2); \
            float rs2 = rs * rs; \
            acc += wl * (cross * cross * (rs2 * rs2 * rs)); \
        } }
    DOSEG(0, 0,  B0)
    DOSEG(1, B0, B1)
    DOSEG(2, B1, B2)
    DOSEG(3, B2, B3)
    DOSEG(4, B3, 1000)
    #undef DOSEG

    #pragma unroll
    for (int m = 32; m >= 1; m >>= 1) acc += __shfl_xor(acc, m, 64);
    if (lane == 0) out_integ[e] = (1.f / 999.f) / 3.f * acc;
}

extern "C" void kernel_launch(void* const* d_in, const int* in_sizes, int n_in,
                              void* d_out, int out_size, void* d_ws, size_t ws_size,
                              hipStream_t stream) {
    const float* x  = (const float*)d_in[0];
    const float* P  = (const float*)d_in[1];
    const float* W1 = (const float*)d_in[2];
    const float* b1 = (const float*)d_in[3];
    const float* W2 = (const float*)d_in[4];
    const float* b2 = (const float*)d_in[5];
    const float* W3 = (const float*)d_in[6];
    const float* b3 = (const float*)d_in[7];
    float* out_integ = (float*)d_out;
    float* out_knots = out_integ + BATCH;

    float* wsf    = (float*)d_ws;
    float* logits = wsf;               // BATCH * 8 floats
    float* coefb  = wsf + BATCH * 8;   // BATCH * 64 floats

    k1_mlp<<<dim3(BATCH / 8), dim3(256), 0, stream>>>(x, W1, b1, W2, b2, W3, b3, logits);
    k2_prep<<<dim3(BATCH / 8), dim3(64), 0, stream>>>(P, logits, coefb, out_knots);
    k3_eval<<<dim3(BATCH / 4), dim3(256), 0, stream>>>(coefb, out_integ);
}

// Round 7
// 29.954 us; speedup vs baseline: 1.6599x; 1.1037x over previous
//
#include <hip/hip_runtime.h>
#include <math.h>

#define BATCH 4096
#define NPTS 1000

// Within-wave LDS producer->consumer fence (LDS ops are memory ops; the
// clobber orders them, sched_barrier stops migration).
#define WSYNC() do { asm volatile("s_waitcnt lgkmcnt(0)" ::: "memory"); \
                     __builtin_amdgcn_sched_barrier(0); } while (0)

// fast 1-ulp reciprocal (v_rcp_f32) — used only downstream of the knots
__device__ __forceinline__ float frcp(float v) { return __builtin_amdgcn_rcpf(v); }

// ==================== K12: MLP -> logits -> prep -> coeffs ====================
// 8 elements/block. Waves 0-3 run the MLP; wave 0 then runs the prep
// (softmax/A/GE/backsub/coeffs) for all 8 elements (8 lanes each).
__global__ __launch_bounds__(256) void k12_mlp_prep(
    const float* __restrict__ x, const float* __restrict__ P,
    const float* __restrict__ W1, const float* __restrict__ b1,
    const float* __restrict__ W2, const float* __restrict__ b2,
    const float* __restrict__ W3, const float* __restrict__ b3,
    float* __restrict__ coef, float* __restrict__ out_knots)
{
    __shared__ float s_h1[8][128];
    __shared__ float s_part[4][4][5];
    __shared__ float LA[8][8][10];
    __shared__ float LQ[8][16];
    __shared__ float LR[8][16];

    const int tid = threadIdx.x;
    const int wv = tid >> 6, lane = tid & 63;
    const int p = tid >> 7, row = tid & 127;
    const int b0 = blockIdx.x * 8;

    // M1: h1 rows for 4 elements
    {
        float4 w0 = ((const float4*)(W1 + row * 8))[0];
        float4 w1 = ((const float4*)(W1 + row * 8))[1];
        float bb = b1[row];
        #pragma unroll
        for (int k = 0; k < 4; ++k) {
            const float* xr = x + (b0 + p * 4 + k) * 8;
            float4 xa = ((const float4*)xr)[0];
            float4 xb = ((const float4*)xr)[1];
            float h = bb + w0.x*xa.x + w0.y*xa.y + w0.z*xa.z + w0.w*xa.w
                         + w1.x*xb.x + w1.y*xb.y + w1.z*xb.z + w1.w*xb.w;
            s_h1[p * 4 + k][row] = fmaxf(h, 0.f);
        }
    }
    __syncthreads();

    // M2: h2[row] for 4 elements (4 independent FMA chains)
    float bb2 = b2[row];
    float a0 = bb2, a1 = bb2, a2 = bb2, a3 = bb2;
    {
        const float4* wr = (const float4*)(W2 + row * 128);
        const float4* h0 = (const float4*)s_h1[p * 4 + 0];
        const float4* h1 = (const float4*)s_h1[p * 4 + 1];
        const float4* h2p = (const float4*)s_h1[p * 4 + 2];
        const float4* h3 = (const float4*)s_h1[p * 4 + 3];
        #pragma unroll 8
        for (int c4 = 0; c4 < 32; ++c4) {
            float4 w = wr[c4];
            float4 ha = h0[c4], hb = h1[c4], hc = h2p[c4], hd = h3[c4];
            a0 += w.x*ha.x + w.y*ha.y + w.z*ha.z + w.w*ha.w;
            a1 += w.x*hb.x + w.y*hb.y + w.z*hb.z + w.w*hb.w;
            a2 += w.x*hc.x + w.y*hc.y + w.z*hc.z + w.w*hc.w;
            a3 += w.x*hd.x + w.y*hd.y + w.z*hd.z + w.w*hd.w;
        }
    }
    float h2_0 = fmaxf(a0, 0.f), h2_1 = fmaxf(a1, 0.f);
    float h2_2 = fmaxf(a2, 0.f), h2_3 = fmaxf(a3, 0.f);

    // M3: logit partials via butterflies
    #pragma unroll
    for (int c = 0; c < 5; ++c) {
        float wc = W3[c * 128 + row];
        float p0 = wc * h2_0, p1 = wc * h2_1, p2 = wc * h2_2, p3 = wc * h2_3;
        #pragma unroll
        for (int m = 32; m >= 1; m >>= 1) {
            p0 += __shfl_xor(p0, m, 64);
            p1 += __shfl_xor(p1, m, 64);
            p2 += __shfl_xor(p2, m, 64);
            p3 += __shfl_xor(p3, m, 64);
        }
        if (lane == 0) {
            s_part[wv][0][c] = p0; s_part[wv][1][c] = p1;
            s_part[wv][2][c] = p2; s_part[wv][3][c] = p3;
        }
    }
    __syncthreads();
    if (wv != 0) return;

    // ---------------- prep on wave 0: lane = el*8 + r ----------------
    const int el = lane >> 3, r = lane & 7;
    const int e = b0 + el;
    const int pw = (el >> 2) * 2;

    // softmax + cumsum -> knots (exact math: knots are a checked output)
    float lg0 = s_part[pw][el & 3][0] + s_part[pw + 1][el & 3][0] + b3[0];
    float lg1 = s_part[pw][el & 3][1] + s_part[pw + 1][el & 3][1] + b3[1];
    float lg2 = s_part[pw][el & 3][2] + s_part[pw + 1][el & 3][2] + b3[2];
    float lg3 = s_part[pw][el & 3][3] + s_part[pw + 1][el & 3][3] + b3[3];
    float lg4 = s_part[pw][el & 3][4] + s_part[pw + 1][el & 3][4] + b3[4];
    float mx = fmaxf(fmaxf(fmaxf(fmaxf(lg0, lg1), lg2), lg3), lg4);
    float e0 = expf(lg0-mx), e1 = expf(lg1-mx), e2 = expf(lg2-mx),
          e3 = expf(lg3-mx), e4 = expf(lg4-mx);
    float s = e0 + e1 + e2 + e3 + e4;
    float xs0 = e0/s, xs1 = e1/s, xs2 = e2/s, xs3 = e3/s;
    float c0 = xs0, c1 = c0 + xs1, c2 = c1 + xs2, c3 = c2 + xs3;
    float w4 = xs0 + (c0 - xs0);
    float w5 = xs1 + (c1 - xs1);
    float w6 = xs2 + (c2 - xs2);
    float w7 = xs3 + (c3 - xs3);

    // knots output + w-span stash for K3
    {
        float kv = (r < 4) ? 0.f : (r == 4 ? w4 : r == 5 ? w5 : r == 6 ? w6 : w7);
        out_knots[e * 12 + r] = kv;
        if (r < 4) {
            out_knots[e * 12 + 8 + r] = 1.f;
            coef[e * 64 + 60 + r] = (r == 0 ? w4 : r == 1 ? w5 : r == 2 ? w6 : w7);
        }
    }

    // basis row recurrence per lane (rows 1..5), static-indexed, rcp divides
    const float ka[12] = {0.f,0.f,0.f,0.f,w4,w5,w6,w7,1.f,1.f,1.f,1.f};
    float t = (r == 2) ? w4 : (r == 3) ? w5 : (r == 4) ? w6 : (r == 5) ? w7 : 0.f;
    float N[11];
    #pragma unroll
    for (int i = 0; i < 11; ++i)
        N[i] = (t >= ka[i] && t < ka[i+1]) ? 1.f : 0.f;
    #pragma unroll
    for (int pq = 1; pq <= 3; ++pq) {
        #pragma unroll
        for (int i = 0; i < 10; ++i) {
            if (i < 10 - pq) {   // m = 10-pq, replicates ref's partial update
                float da = ka[i+pq] - ka[i];
                float av = (da != 0.f) ? (t - ka[i]) * frcp(da) : 0.f;
                float db = ka[i+pq+1] - ka[i+1];
                float bv = (db != 0.f) ? (ka[i+pq+1] - t) * frcp(db) : 0.f;
                N[i] = N[i] * av + N[i+1] * bv;
            }
        }
    }

    // assemble this lane's A row + rhs in registers
    float a[10];
    #pragma unroll
    for (int c = 0; c < 8; ++c) {
        float v0 = (c==0) ? w5 : (c==1) ? (-w4-w5) : (c==2) ? w4 : 0.f;
        float v6 = (c==7) ? 1.f : 0.f;
        float v7 = (c==5) ? (1.f-w7) : (c==6) ? (w7+w6-2.f) : (c==7) ? (1.f-w6) : 0.f;
        float vb = (r==0) ? v0 : (r==6) ? v6 : v7;
        a[c] = (r >= 1 && r <= 5) ? N[c] : vb;
    }
    {
        float px = 0.f, py = 0.f;
        if (r >= 1 && r <= 6) {
            px = P[e * 12 + (r-1) * 2 + 0];
            py = P[e * 12 + (r-1) * 2 + 1];
        }
        a[8] = px; a[9] = py;
    }

    // GE with partial pivoting: 8-lane groups, proven shfl path (rcp factor)
    int done = 0, pcol = 7;
    #pragma unroll
    for (int col = 0; col < 8; ++col) {
        float bv = done ? -1.f : fabsf(a[col]);
        int bi = lane;
        #pragma unroll
        for (int m = 1; m <= 4; m <<= 1) {
            float ov = __shfl_xor(bv, m, 64);
            int   oi = __shfl_xor(bi, m, 64);
            if (ov > bv || (ov == bv && oi < bi)) { bv = ov; bi = oi; }
        }
        float pr[10];
        #pragma unroll
        for (int c = 0; c < 10; ++c) pr[c] = __shfl(a[c], bi, 64);
        if (lane == bi) { done = 1; pcol = col; }
        else if (!done) {
            float f = a[col] * frcp(pr[col]);
            #pragma unroll
            for (int c = 0; c < 10; ++c) if (c > col) a[c] -= f * pr[c];
        }
    }
    #pragma unroll
    for (int c = 0; c < 10; ++c) LA[el][pcol][c] = a[c];
    WSYNC();

    // back-substitution (parity lanes 0/1 per group) + Q/R
    if (r < 2) {
        const int par = r;
        float C[8];
        #pragma unroll
        for (int col = 7; col >= 0; --col) {
            float sv = LA[el][col][8 + par];
            #pragma unroll
            for (int c = col + 1; c < 8; ++c) sv -= LA[el][col][c] * C[c];
            C[col] = sv * frcp(LA[el][col][col]);
        }
        float Qr[7], Rr[6];
        const float dq[7] = { w4, w5, w6, w7 - w4, 1.f - w5, 1.f - w6, 1.f - w7 };
        #pragma unroll
        for (int i = 0; i < 7; ++i) Qr[i] = (3.f * frcp(dq[i])) * (C[i+1] - C[i]);
        const float dr[6] = { w4, w5, w6 - w4, w7 - w5, 1.f - w6, 1.f - w7 };
        #pragma unroll
        for (int i = 0; i < 6; ++i) Rr[i] = (2.f * frcp(dr[i])) * (Qr[i+1] - Qr[i]);
        #pragma unroll
        for (int i = 0; i < 7; ++i) LQ[el][i*2+par] = Qr[i];
        #pragma unroll
        for (int i = 0; i < 6; ++i) LR[el][i*2+par] = Rr[i];
    }
    WSYNC();

    // per-segment polynomial coeffs (round-4 formulas, rcp), lane r<5 = segment
    if (r < 5) {
        const int s5 = r;
        float k2 = (s5 <= 1) ? 0.f : (s5 == 2) ? w4 : (s5 == 3) ? w5 : w6;  // ka[2+s]
        float k3 = (s5 == 0) ? 0.f : (s5 == 1) ? w4 : (s5 == 2) ? w5 : (s5 == 3) ? w6 : w7;
        float k4 = (s5 == 0) ? w4 : (s5 == 1) ? w5 : (s5 == 2) ? w6 : (s5 == 3) ? w7 : 1.f;
        float k5 = (s5 == 0) ? w5 : (s5 == 1) ? w6 : (s5 == 2) ? w7 : 1.f;
        float q0x = LQ[el][s5*2],     q0y = LQ[el][s5*2+1];
        float q1x = LQ[el][(s5+1)*2], q1y = LQ[el][(s5+1)*2+1];
        float q2x = LQ[el][(s5+2)*2], q2y = LQ[el][(s5+2)*2+1];
        float r0x = LR[el][s5*2],     r0y = LR[el][s5*2+1];
        float r1x = LR[el][(s5+1)*2], r1y = LR[el][(s5+1)*2+1];
        float r42 = frcp(k4-k2), r53 = frcp(k5-k3), r43 = frcp(k4-k3);
        float A0x = (k4*q0x - k2*q1x)*r42, B0x = (q1x-q0x)*r42;
        float A1x = (k5*q1x - k3*q2x)*r53, B1x = (q2x-q1x)*r53;
        float c0x = r43*(k4*A0x - k3*A1x);
        float c1x = r43*(k4*B0x - A0x + A1x - k3*B1x);
        float c2x = r43*(B1x - B0x);
        float e0x = r43*(k4*r0x - k3*r1x);
        float e1x = r43*(r1x - r0x);
        float A0y = (k4*q0y - k2*q1y)*r42, B0y = (q1y-q0y)*r42;
        float A1y = (k5*q1y - k3*q2y)*r53, B1y = (q2y-q1y)*r53;
        float c0y = r43*(k4*A0y - k3*A1y);
        float c1y = r43*(k4*B0y - A0y + A1y - k3*B1y);
        float c2y = r43*(B1y - B0y);
        float e0y = r43*(k4*r0y - k3*r1y);
        float e1y = r43*(r1y - r0y);
        float* cb = coef + e * 64 + s5 * 12;
        cb[0] = c0x; cb[1] = c1x; cb[2]  = c2x; cb[3]  = c0y;
        cb[4] = c1y; cb[5] = c2y; cb[6]  = e0x; cb[7]  = e1x;
        cb[8] = e0y; cb[9] = e1y; cb[10] = 0.f; cb[11] = 0.f;
    }
}

// ============================ K3: eval =====================================
// 1 wave = 1 element. Segment-ordered loop; coeffs hoisted to scalars via
// readlane; inner loop is pure VALU (no LDS, no divergence). (round-5 verbatim)
__global__ __launch_bounds__(256) void k3_eval(
    const float* __restrict__ coef, float* __restrict__ out_integ)
{
    const int tid = threadIdx.x, wv = tid >> 6, lane = tid & 63;
    const int e = blockIdx.x * 4 + wv;
    const float c999 = 1.f / 999.f;

    float v = coef[e * 64 + lane];
    int vi = __float_as_int(v);
    float w4 = __int_as_float(__builtin_amdgcn_readlane(vi, 60));
    float w5 = __int_as_float(__builtin_amdgcn_readlane(vi, 61));
    float w6 = __int_as_float(__builtin_amdgcn_readlane(vi, 62));
    float w7 = __int_as_float(__builtin_amdgcn_readlane(vi, 63));

    // first idx with idx*c999 > w  (exact same predicate as ref's k-count)
    auto bsearch = [&](float w) {
        int lo = 0, hi = 1000;
        #pragma unroll
        for (int it = 0; it < 10; ++it) {
            int mid = (lo + hi) >> 1;
            bool pr = ((float)mid * c999 > w);
            hi = pr ? mid : hi;
            lo = pr ? lo : (mid + 1);
        }
        return lo;
    };
    int B0 = bsearch(w4), B1 = bsearch(w5), B2 = bsearch(w6), B3 = bsearch(w7);

    float acc = 0.f;
    #define DOSEG(S, LOE, HIE) { \
        float cx0 = __int_as_float(__builtin_amdgcn_readlane(vi, (S)*12+0)); \
        float cx1 = __int_as_float(__builtin_amdgcn_readlane(vi, (S)*12+1)); \
        float cx2 = __int_as_float(__builtin_amdgcn_readlane(vi, (S)*12+2)); \
        float cy0 = __int_as_float(__builtin_amdgcn_readlane(vi, (S)*12+3)); \
        float cy1 = __int_as_float(__builtin_amdgcn_readlane(vi, (S)*12+4)); \
        float cy2 = __int_as_float(__builtin_amdgcn_readlane(vi, (S)*12+5)); \
        float ex0 = __int_as_float(__builtin_amdgcn_readlane(vi, (S)*12+6)); \
        float ex1 = __int_as_float(__builtin_amdgcn_readlane(vi, (S)*12+7)); \
        float ey0 = __int_as_float(__builtin_amdgcn_readlane(vi, (S)*12+8)); \
        float ey1 = __int_as_float(__builtin_amdgcn_readlane(vi, (S)*12+9)); \
        int lo = (LOE), hi = (HIE); \
        float wl = ((lo + lane) & 1) ? 4.f : 2.f; \
        for (int idx = lo + lane; idx < hi; idx += 64) { \
            float tt = (float)idx * c999; \
            float spx = (cx2 * tt + cx1) * tt + cx0; \
            float spy = (cy2 * tt + cy1) * tt + cy0; \
            float sdx = ex1 * tt + ex0; \
            float sdy = ey1 * tt + ey0; \
            float s2 = spx * spx + spy * spy; \
            float cross = spx * sdy - spy * sdx; \
            float rs = rsqrtf(s2); \
            float rs2 = rs * rs; \
            acc += wl * (cross * cross * (rs2 * rs2 * rs)); \
        } }
    DOSEG(0, 0,  B0)
    DOSEG(1, B0, B1)
    DOSEG(2, B1, B2)
    DOSEG(3, B2, B3)
    DOSEG(4, B3, 1000)
    #undef DOSEG

    #pragma unroll
    for (int m = 32; m >= 1; m >>= 1) acc += __shfl_xor(acc, m, 64);
    if (lane == 0) out_integ[e] = (1.f / 999.f) / 3.f * acc;
}

extern "C" void kernel_launch(void* const* d_in, const int* in_sizes, int n_in,
                              void* d_out, int out_size, void* d_ws, size_t ws_size,
                              hipStream_t stream) {
    const float* x  = (const float*)d_in[0];
    const float* P  = (const float*)d_in[1];
    const float* W1 = (const float*)d_in[2];
    const float* b1 = (const float*)d_in[3];
    const float* W2 = (const float*)d_in[4];
    const float* b2 = (const float*)d_in[5];
    const float* W3 = (const float*)d_in[6];
    const float* b3 = (const float*)d_in[7];
    float* out_integ = (float*)d_out;
    float* out_knots = out_integ + BATCH;

    float* coefb = (float*)d_ws;   // BATCH * 64 floats

    k12_mlp_prep<<<dim3(BATCH / 8), dim3(256), 0, stream>>>(
        x, P, W1, b1, W2, b2, W3, b3, coefb, out_knots);
    k3_eval<<<dim3(BATCH / 4), dim3(256), 0, stream>>>(coefb, out_integ);
}

// Round 8
// 28.836 us; speedup vs baseline: 1.7243x; 1.0388x over previous
//
#include <hip/hip_runtime.h>
#include <math.h>

#define BATCH 4096
#define NPTS 1000

// Within-wave LDS producer->consumer fence (LDS ops are memory ops; the
// clobber orders them, sched_barrier stops migration).
#define WSYNC() do { asm volatile("s_waitcnt lgkmcnt(0)" ::: "memory"); \
                     __builtin_amdgcn_sched_barrier(0); } while (0)

// fast 1-ulp reciprocal (v_rcp_f32) — used only downstream of the knots
__device__ __forceinline__ float frcp(float v) { return __builtin_amdgcn_rcpf(v); }

// =============== single fused kernel: MLP -> prep -> eval ===============
// 8 elements/block, 256 threads. Waves 0-3: MLP. Wave 0: prep (8 lanes per
// element). All waves: eval (2 elements per wave), coefs via LDS.
__global__ __launch_bounds__(256, 8) void net2_one(
    const float* __restrict__ x, const float* __restrict__ P,
    const float* __restrict__ W1, const float* __restrict__ b1,
    const float* __restrict__ W2, const float* __restrict__ b2,
    const float* __restrict__ W3, const float* __restrict__ b3,
    float* __restrict__ out_integ, float* __restrict__ out_knots)
{
    __shared__ float s_h1[8][128];
    __shared__ float s_part[4][4][5];
    __shared__ float LA[8][8][10];
    __shared__ float LQ[8][16];
    __shared__ float LR[8][16];
    __shared__ float s_coef[8][64];

    const int tid = threadIdx.x;
    const int wv = tid >> 6, lane = tid & 63;
    const int p = tid >> 7, row = tid & 127;
    const int b0 = blockIdx.x * 8;

    // ---------------- M1: h1 rows for 4 elements ----------------
    {
        float4 w0 = ((const float4*)(W1 + row * 8))[0];
        float4 w1 = ((const float4*)(W1 + row * 8))[1];
        float bb = b1[row];
        #pragma unroll
        for (int k = 0; k < 4; ++k) {
            const float* xr = x + (b0 + p * 4 + k) * 8;
            float4 xa = ((const float4*)xr)[0];
            float4 xb = ((const float4*)xr)[1];
            float h = bb + w0.x*xa.x + w0.y*xa.y + w0.z*xa.z + w0.w*xa.w
                         + w1.x*xb.x + w1.y*xb.y + w1.z*xb.z + w1.w*xb.w;
            s_h1[p * 4 + k][row] = fmaxf(h, 0.f);
        }
    }
    __syncthreads();

    // ---------------- M2: h2[row] for 4 elements ----------------
    float bb2 = b2[row];
    float a0 = bb2, a1 = bb2, a2 = bb2, a3 = bb2;
    {
        const float4* wr = (const float4*)(W2 + row * 128);
        const float4* h0 = (const float4*)s_h1[p * 4 + 0];
        const float4* h1 = (const float4*)s_h1[p * 4 + 1];
        const float4* h2p = (const float4*)s_h1[p * 4 + 2];
        const float4* h3 = (const float4*)s_h1[p * 4 + 3];
        #pragma unroll 8
        for (int c4 = 0; c4 < 32; ++c4) {
            float4 w = wr[c4];
            float4 ha = h0[c4], hb = h1[c4], hc = h2p[c4], hd = h3[c4];
            a0 += w.x*ha.x + w.y*ha.y + w.z*ha.z + w.w*ha.w;
            a1 += w.x*hb.x + w.y*hb.y + w.z*hb.z + w.w*hb.w;
            a2 += w.x*hc.x + w.y*hc.y + w.z*hc.z + w.w*hc.w;
            a3 += w.x*hd.x + w.y*hd.y + w.z*hd.z + w.w*hd.w;
        }
    }
    float h2_0 = fmaxf(a0, 0.f), h2_1 = fmaxf(a1, 0.f);
    float h2_2 = fmaxf(a2, 0.f), h2_3 = fmaxf(a3, 0.f);

    // ---------------- M3: logit partials via butterflies ----------------
    #pragma unroll
    for (int c = 0; c < 5; ++c) {
        float wc = W3[c * 128 + row];
        float p0 = wc * h2_0, p1 = wc * h2_1, p2 = wc * h2_2, p3 = wc * h2_3;
        #pragma unroll
        for (int m = 32; m >= 1; m >>= 1) {
            p0 += __shfl_xor(p0, m, 64);
            p1 += __shfl_xor(p1, m, 64);
            p2 += __shfl_xor(p2, m, 64);
            p3 += __shfl_xor(p3, m, 64);
        }
        if (lane == 0) {
            s_part[wv][0][c] = p0; s_part[wv][1][c] = p1;
            s_part[wv][2][c] = p2; s_part[wv][3][c] = p3;
        }
    }
    __syncthreads();

    // ---------------- prep on wave 0: lane = el*8 + r ----------------
    if (wv == 0) {
        const int el = lane >> 3, r = lane & 7;
        const int e = b0 + el;
        const int pw = (el >> 2) * 2;

        // softmax + cumsum -> knots (exact math: knots are a checked output)
        float lg0 = s_part[pw][el & 3][0] + s_part[pw + 1][el & 3][0] + b3[0];
        float lg1 = s_part[pw][el & 3][1] + s_part[pw + 1][el & 3][1] + b3[1];
        float lg2 = s_part[pw][el & 3][2] + s_part[pw + 1][el & 3][2] + b3[2];
        float lg3 = s_part[pw][el & 3][3] + s_part[pw + 1][el & 3][3] + b3[3];
        float lg4 = s_part[pw][el & 3][4] + s_part[pw + 1][el & 3][4] + b3[4];
        float mx = fmaxf(fmaxf(fmaxf(fmaxf(lg0, lg1), lg2), lg3), lg4);
        float e0 = expf(lg0-mx), e1 = expf(lg1-mx), e2 = expf(lg2-mx),
              e3 = expf(lg3-mx), e4 = expf(lg4-mx);
        float s = e0 + e1 + e2 + e3 + e4;
        float xs0 = e0/s, xs1 = e1/s, xs2 = e2/s, xs3 = e3/s;
        float c0 = xs0, c1 = c0 + xs1, c2 = c1 + xs2, c3 = c2 + xs3;
        float w4 = xs0 + (c0 - xs0);
        float w5 = xs1 + (c1 - xs1);
        float w6 = xs2 + (c2 - xs2);
        float w7 = xs3 + (c3 - xs3);

        // knots output + w-span stash for eval
        {
            float kv = (r < 4) ? 0.f : (r == 4 ? w4 : r == 5 ? w5 : r == 6 ? w6 : w7);
            out_knots[e * 12 + r] = kv;
            if (r < 4) {
                out_knots[e * 12 + 8 + r] = 1.f;
                s_coef[el][60 + r] = (r == 0 ? w4 : r == 1 ? w5 : r == 2 ? w6 : w7);
            }
        }

        // basis row recurrence per lane (rows 1..5), static-indexed, rcp divides
        const float ka[12] = {0.f,0.f,0.f,0.f,w4,w5,w6,w7,1.f,1.f,1.f,1.f};
        float t = (r == 2) ? w4 : (r == 3) ? w5 : (r == 4) ? w6 : (r == 5) ? w7 : 0.f;
        float N[11];
        #pragma unroll
        for (int i = 0; i < 11; ++i)
            N[i] = (t >= ka[i] && t < ka[i+1]) ? 1.f : 0.f;
        #pragma unroll
        for (int pq = 1; pq <= 3; ++pq) {
            #pragma unroll
            for (int i = 0; i < 10; ++i) {
                if (i < 10 - pq) {   // m = 10-pq, replicates ref's partial update
                    float da = ka[i+pq] - ka[i];
                    float av = (da != 0.f) ? (t - ka[i]) * frcp(da) : 0.f;
                    float db = ka[i+pq+1] - ka[i+1];
                    float bv = (db != 0.f) ? (ka[i+pq+1] - t) * frcp(db) : 0.f;
                    N[i] = N[i] * av + N[i+1] * bv;
                }
            }
        }

        // assemble this lane's A row + rhs in registers
        float a[10];
        #pragma unroll
        for (int c = 0; c < 8; ++c) {
            float v0 = (c==0) ? w5 : (c==1) ? (-w4-w5) : (c==2) ? w4 : 0.f;
            float v6 = (c==7) ? 1.f : 0.f;
            float v7 = (c==5) ? (1.f-w7) : (c==6) ? (w7+w6-2.f) : (c==7) ? (1.f-w6) : 0.f;
            float vb = (r==0) ? v0 : (r==6) ? v6 : v7;
            a[c] = (r >= 1 && r <= 5) ? N[c] : vb;
        }
        {
            float px = 0.f, py = 0.f;
            if (r >= 1 && r <= 6) {
                px = P[e * 12 + (r-1) * 2 + 0];
                py = P[e * 12 + (r-1) * 2 + 1];
            }
            a[8] = px; a[9] = py;
        }

        // GE with partial pivoting: 8-lane groups, proven shfl path (rcp factor)
        int done = 0, pcol = 7;
        #pragma unroll
        for (int col = 0; col < 8; ++col) {
            float bv = done ? -1.f : fabsf(a[col]);
            int bi = lane;
            #pragma unroll
            for (int m = 1; m <= 4; m <<= 1) {
                float ov = __shfl_xor(bv, m, 64);
                int   oi = __shfl_xor(bi, m, 64);
                if (ov > bv || (ov == bv && oi < bi)) { bv = ov; bi = oi; }
            }
            float pr[10];
            #pragma unroll
            for (int c = 0; c < 10; ++c) pr[c] = __shfl(a[c], bi, 64);
            if (lane == bi) { done = 1; pcol = col; }
            else if (!done) {
                float f = a[col] * frcp(pr[col]);
                #pragma unroll
                for (int c = 0; c < 10; ++c) if (c > col) a[c] -= f * pr[c];
            }
        }
        #pragma unroll
        for (int c = 0; c < 10; ++c) LA[el][pcol][c] = a[c];
        WSYNC();

        // back-substitution (parity lanes 0/1 per group) + Q/R
        if (r < 2) {
            const int par = r;
            float C[8];
            #pragma unroll
            for (int col = 7; col >= 0; --col) {
                float sv = LA[el][col][8 + par];
                #pragma unroll
                for (int c = col + 1; c < 8; ++c) sv -= LA[el][col][c] * C[c];
                C[col] = sv * frcp(LA[el][col][col]);
            }
            float Qr[7], Rr[6];
            const float dq[7] = { w4, w5, w6, w7 - w4, 1.f - w5, 1.f - w6, 1.f - w7 };
            #pragma unroll
            for (int i = 0; i < 7; ++i) Qr[i] = (3.f * frcp(dq[i])) * (C[i+1] - C[i]);
            const float dr[6] = { w4, w5, w6 - w4, w7 - w5, 1.f - w6, 1.f - w7 };
            #pragma unroll
            for (int i = 0; i < 6; ++i) Rr[i] = (2.f * frcp(dr[i])) * (Qr[i+1] - Qr[i]);
            #pragma unroll
            for (int i = 0; i < 7; ++i) LQ[el][i*2+par] = Qr[i];
            #pragma unroll
            for (int i = 0; i < 6; ++i) LR[el][i*2+par] = Rr[i];
        }
        WSYNC();

        // per-segment polynomial coeffs (proven formulas, rcp), lane r<5 = segment
        if (r < 5) {
            const int s5 = r;
            float k2 = (s5 <= 1) ? 0.f : (s5 == 2) ? w4 : (s5 == 3) ? w5 : w6;  // ka[2+s]
            float k3 = (s5 == 0) ? 0.f : (s5 == 1) ? w4 : (s5 == 2) ? w5 : (s5 == 3) ? w6 : w7;
            float k4 = (s5 == 0) ? w4 : (s5 == 1) ? w5 : (s5 == 2) ? w6 : (s5 == 3) ? w7 : 1.f;
            float k5 = (s5 == 0) ? w5 : (s5 == 1) ? w6 : (s5 == 2) ? w7 : 1.f;
            float q0x = LQ[el][s5*2],     q0y = LQ[el][s5*2+1];
            float q1x = LQ[el][(s5+1)*2], q1y = LQ[el][(s5+1)*2+1];
            float q2x = LQ[el][(s5+2)*2], q2y = LQ[el][(s5+2)*2+1];
            float r0x = LR[el][s5*2],     r0y = LR[el][s5*2+1];
            float r1x = LR[el][(s5+1)*2], r1y = LR[el][(s5+1)*2+1];
            float r42 = frcp(k4-k2), r53 = frcp(k5-k3), r43 = frcp(k4-k3);
            float A0x = (k4*q0x - k2*q1x)*r42, B0x = (q1x-q0x)*r42;
            float A1x = (k5*q1x - k3*q2x)*r53, B1x = (q2x-q1x)*r53;
            float c0x = r43*(k4*A0x - k3*A1x);
            float c1x = r43*(k4*B0x - A0x + A1x - k3*B1x);
            float c2x = r43*(B1x - B0x);
            float e0x = r43*(k4*r0x - k3*r1x);
            float e1x = r43*(r1x - r0x);
            float A0y = (k4*q0y - k2*q1y)*r42, B0y = (q1y-q0y)*r42;
            float A1y = (k5*q1y - k3*q2y)*r53, B1y = (q2y-q1y)*r53;
            float c0y = r43*(k4*A0y - k3*A1y);
            float c1y = r43*(k4*B0y - A0y + A1y - k3*B1y);
            float c2y = r43*(B1y - B0y);
            float e0y = r43*(k4*r0y - k3*r1y);
            float e1y = r43*(r1y - r0y);
            float* cb = &s_coef[el][s5 * 12];
            cb[0] = c0x; cb[1] = c1x; cb[2]  = c2x; cb[3]  = c0y;
            cb[4] = c1y; cb[5] = c2y; cb[6]  = e0x; cb[7]  = e1x;
            cb[8] = e0y; cb[9] = e1y; cb[10] = 0.f; cb[11] = 0.f;
        }
    }
    __syncthreads();

    // ---------------- eval: each wave evaluates 2 elements ----------------
    const float c999 = 1.f / 999.f;
    #pragma unroll
    for (int q = 0; q < 2; ++q) {
        const int el = wv * 2 + q;
        const int e = b0 + el;
        float v = s_coef[el][lane];
        int vi = __float_as_int(v);
        float w4 = __int_as_float(__builtin_amdgcn_readlane(vi, 60));
        float w5 = __int_as_float(__builtin_amdgcn_readlane(vi, 61));
        float w6 = __int_as_float(__builtin_amdgcn_readlane(vi, 62));
        float w7 = __int_as_float(__builtin_amdgcn_readlane(vi, 63));

        // first idx with idx*c999 > w  (exact same predicate as ref's k-count)
        auto bsearch = [&](float w) {
            int lo = 0, hi = 1000;
            #pragma unroll
            for (int it = 0; it < 10; ++it) {
                int mid = (lo + hi) >> 1;
                bool pr = ((float)mid * c999 > w);
                hi = pr ? mid : hi;
                lo = pr ? lo : (mid + 1);
            }
            return lo;
        };
        int B0 = bsearch(w4), B1 = bsearch(w5), B2 = bsearch(w6), B3 = bsearch(w7);

        float acc = 0.f;
        #define DOSEG(S, LOE, HIE) { \
            float cx0 = __int_as_float(__builtin_amdgcn_readlane(vi, (S)*12+0)); \
            float cx1 = __int_as_float(__builtin_amdgcn_readlane(vi, (S)*12+1)); \
            float cx2 = __int_as_float(__builtin_amdgcn_readlane(vi, (S)*12+2)); \
            float cy0 = __int_as_float(__builtin_amdgcn_readlane(vi, (S)*12+3)); \
            float cy1 = __int_as_float(__builtin_amdgcn_readlane(vi, (S)*12+4)); \
            float cy2 = __int_as_float(__builtin_amdgcn_readlane(vi, (S)*12+5)); \
            float ex0 = __int_as_float(__builtin_amdgcn_readlane(vi, (S)*12+6)); \
            float ex1 = __int_as_float(__builtin_amdgcn_readlane(vi, (S)*12+7)); \
            float ey0 = __int_as_float(__builtin_amdgcn_readlane(vi, (S)*12+8)); \
            float ey1 = __int_as_float(__builtin_amdgcn_readlane(vi, (S)*12+9)); \
            int lo = (LOE), hi = (HIE); \
            float wl = ((lo + lane) & 1) ? 4.f : 2.f; \
            for (int idx = lo + lane; idx < hi; idx += 64) { \
                float tt = (float)idx * c999; \
                float spx = (cx2 * tt + cx1) * tt + cx0; \
                float spy = (cy2 * tt + cy1) * tt + cy0; \
                float sdx = ex1 * tt + ex0; \
                float sdy = ey1 * tt + ey0; \
                float s2 = spx * spx + spy * spy; \
                float cross = spx * sdy - spy * sdx; \
                float rs = rsqrtf(s2); \
                float rs2 = rs * rs; \
                acc += wl * (cross * cross * (rs2 * rs2 * rs)); \
            } }
        DOSEG(0, 0,  B0)
        DOSEG(1, B0, B1)
        DOSEG(2, B1, B2)
        DOSEG(3, B2, B3)
        DOSEG(4, B3, 1000)
        #undef DOSEG

        #pragma unroll
        for (int m = 32; m >= 1; m >>= 1) acc += __shfl_xor(acc, m, 64);
        if (lane == 0) out_integ[e] = (1.f / 999.f) / 3.f * acc;
    }
}

extern "C" void kernel_launch(void* const* d_in, const int* in_sizes, int n_in,
                              void* d_out, int out_size, void* d_ws, size_t ws_size,
                              hipStream_t stream) {
    const float* x  = (const float*)d_in[0];
    const float* P  = (const float*)d_in[1];
    const float* W1 = (const float*)d_in[2];
    const float* b1 = (const float*)d_in[3];
    const float* W2 = (const float*)d_in[4];
    const float* b2 = (const float*)d_in[5];
    const float* W3 = (const float*)d_in[6];
    const float* b3 = (const float*)d_in[7];
    float* out_integ = (float*)d_out;
    float* out_knots = out_integ + BATCH;

    net2_one<<<dim3(BATCH / 8), dim3(256), 0, stream>>>(
        x, P, W1, b1, W2, b2, W3, b3, out_integ, out_knots);
}